// Round 10
// baseline (131.940 us; speedup 1.0000x reference)
//
#include <hip/hip_runtime.h>
#include <hip/hip_bf16.h>
#include <math.h>

// Problem constants (B=4096 rows, D=768 features)
#define B_ROWS 4096
#define D_DIM  768

// R10 = the m97 geometry applied to this problem: 128x128 tile, BK=64
// (two BK=32 halves), SINGLE-buffered 32 KB LDS, 4 waves, 2-barrier loop.
// Cross-round delivery data (R6=3.9, R0/R8/R9=6-7, m97@4-domains=14.3 TB/s)
// shows global_load_lds delivery scales ~3.5 TB/s PER RESIDENT BLOCK-DOMAIN;
// 32 KB LDS -> 5 blocks/CU resident (vs 2 all session) is the lever.
// Staged bytes rise to 402 MB (AI 64 vs 85 FLOP/B) but delivery ~doubles.
#define BM 128
#define BN 128
#define BK 32                    // layout/stage granularity; 2 subs per iter
#define NKT (D_DIM / 64)         // 12 K-iterations of K=64
#define KT_STRIDE (B_ROWS * 32)  // ushorts per BK=32 K-tile block in Pb/Tb
#define HALF_USH 8192            // ushorts per K-sub-half in LDS (A 8KB + B 8KB)
#define NBLK ((B_ROWS / BM) * (B_ROWS / BN))   // 32*32 = 1024 workgroups

typedef __attribute__((ext_vector_type(8))) short bf16x8;  // 8 bf16 = 4 VGPRs (MFMA A/B frag)
typedef __attribute__((ext_vector_type(4))) float f32x4;   // MFMA C/D frag

__device__ __forceinline__ unsigned short f32_to_bf16(float x) {
    // round-to-nearest-even; inputs are finite normals
    unsigned int u = __float_as_uint(x);
    return (unsigned short)((u + 0x7fffu + ((u >> 16) & 1u)) >> 16);
}

// async global->LDS, 16 B per lane. LDS dest is WAVE-UNIFORM base; HW writes
// lane L's 16 B at base + L*16 (m97/m104-verified semantics).
__device__ __forceinline__ void async_copy16(const unsigned short* g, unsigned short* l) {
    __builtin_amdgcn_global_load_lds(
        (const __attribute__((address_space(1))) unsigned int*)g,
        (__attribute__((address_space(3))) unsigned int*)l,
        16, 0, 0);
}

// K1: per-row stats + fp32->bf16 conversion into the BLOCKED, PRE-SWIZZLED
// layout Pb[kt32][row][slot] (kt32 = K-tile of 32 elems, 64-B rows, 16-B
// chunk at slot = chunk ^ ((row>>1)&3)).  Unchanged from R8/R9 (verified).
__global__ void __launch_bounds__(256) rowstats_kernel(
    const float* __restrict__ P, const float* __restrict__ T,
    unsigned short* __restrict__ Pb, unsigned short* __restrict__ Tb,
    float* __restrict__ p_sq, float* __restrict__ t_sq,
    float* __restrict__ diagl, float* __restrict__ magr,
    float* __restrict__ rowsum)
{
    const int wave = threadIdx.x >> 6, lane = threadIdx.x & 63;
    const int i = blockIdx.x * 4 + wave;
    const f32x4* prow = (const f32x4*)(P + (size_t)i * D_DIM);
    const f32x4* trow = (const f32x4*)(T + (size_t)i * D_DIM);
    const int swz = (i >> 1) & 3;

    float psq = 0.f, tsq = 0.f, cr = 0.f, l1 = 0.f, tm = 0.f;
    #pragma unroll
    for (int u = 0; u < 3; ++u) {         // 192 float4 per row / 64 lanes
        const int c4 = u * 64 + lane;
        f32x4 p = prow[c4], t = trow[c4];
        #pragma unroll
        for (int k = 0; k < 4; ++k) {
            psq += p[k] * p[k]; tsq += t[k] * t[k]; cr += p[k] * t[k];
            l1 += fabsf(p[k] - t[k]); tm += fabsf(t[k]);
        }
        // blocked-swizzled destination
        const int kt  = c4 >> 3;                 // 8 float4 = 32 elems per tile
        const int cc  = (c4 >> 1) & 3;           // 16-B chunk within tile row
        const int sub = c4 & 1;                  // 8-B half of the chunk
        const size_t doff = (size_t)kt * KT_STRIDE + (size_t)i * 32
                          + (size_t)(((cc ^ swz) << 3) + (sub << 2));
        *(ushort4*)(Pb + doff) = make_ushort4(f32_to_bf16(p[0]), f32_to_bf16(p[1]),
                                              f32_to_bf16(p[2]), f32_to_bf16(p[3]));
        *(ushort4*)(Tb + doff) = make_ushort4(f32_to_bf16(t[0]), f32_to_bf16(t[1]),
                                              f32_to_bf16(t[2]), f32_to_bf16(t[3]));
    }
    #pragma unroll
    for (int m = 1; m < 64; m <<= 1) {
        psq += __shfl_xor(psq, m, 64);
        tsq += __shfl_xor(tsq, m, 64);
        cr  += __shfl_xor(cr,  m, 64);
        l1  += __shfl_xor(l1,  m, 64);
        tm  += __shfl_xor(tm,  m, 64);
    }
    if (lane == 0) {
        p_sq[i] = psq;
        t_sq[i] = tsq;
        float sq = fmaxf(psq + tsq - 2.0f * cr, 0.0f);
        diagl[i] = -sqrtf(sq) * 10.0f;    // logit_ii = -dist/0.1 (the LSE shift)
        magr[i]  = l1 / tm;
        rowsum[i] = 0.0f;
    }
}

// K2: bf16-MFMA cross GEMM + LSE epilogue.  m97 structure: single 32-KB
// buffer, stage -> syncthreads (compiler emits the vmcnt(0) drain) ->
// compute -> syncthreads.  No intra-block pipelining; throughput comes from
// 5 resident block-domains per CU interleaving stage and compute phases.
//
// LDS layout per iteration (K=64 as two K=32 halves):
//   [A half0 8KB][B half0 8KB][A half1 8KB][B half1 8KB]
// Each half in the blocked/pre-swizzled row format (row stride 32 ushorts,
// chunk slot c ^ ((row>>1)&3)); ds_read at slot quad^((row16>>1)&3) ->
// 2-way max bank aliasing (free, m136; 0 conflicts measured all session).
__global__ void __launch_bounds__(256) lse_gemm_kernel(
    const unsigned short* __restrict__ Pb, const unsigned short* __restrict__ Tb,
    const float* __restrict__ p_sq, const float* __restrict__ t_sq,
    const float* __restrict__ diagl, float* __restrict__ rowsum)
{
    __shared__ __align__(16) unsigned short S[2 * HALF_USH];  // 32 KB

    const int tid  = threadIdx.x;
    const int lane = tid & 63, wave = tid >> 6;

    // XCD-aware swizzle (bijective over 1024 blocks): tile grid 32x32;
    // XCD x gets a 16(ti) x 8(tj) chunk -> A 3 MB + B 1.5 MB panel.
    const int flat = blockIdx.x;
    const int xcd  = flat & 7;
    const int s    = flat >> 3;                      // 0..127: slot within XCD
    const int ti   = ((xcd & 1) << 4) + (s & 15);    // 0..31
    const int tj   = ((xcd >> 1) << 3) + (s >> 4);   // 0..31
    const int i0   = ti * BM, j0 = tj * BN;

    // compute mapping: 2x2 wave grid, per-wave output 64(M) x 64(N)
    const int wm = wave >> 1, wn = wave & 1;
    const int row16 = lane & 15, quad = lane >> 4;
    const int slot  = quad ^ ((row16 >> 1) & 3);     // chunk-XOR de-swizzle

    // fragment LDS offsets within a K-half (ushort units)
    int aoff[4], boff[4];
    #pragma unroll
    for (int mt = 0; mt < 4; ++mt)
        aoff[mt] = (wm * 64 + mt * 16 + row16) * BK + (slot << 3);
    #pragma unroll
    for (int nt = 0; nt < 4; ++nt)
        boff[nt] = 4096 + (wn * 64 + nt * 16 + row16) * BK + (slot << 3);

    // staging: 32 x 1KB instrs per iteration (2 halves x (A 8 + B 8 groups)),
    // 8 per wave.  Wave w covers: w=0: half0 A, w=1: half0 B, w=2: half1 A,
    // w=3: half1 B — each instr reads 16 rows x 64 B contiguous (pre-swizzled
    // blocked layout) and writes LDS linearly (base + lane*16 B).
    const int  sub  = wave >> 1;                     // K-half this wave stages
    const bool isB  = wave & 1;
    const unsigned short* gsrc = isB ? Tb : Pb;
    const int  r0g  = isB ? j0 : i0;
    const unsigned short* gp[8];
    int lb[8];
    #pragma unroll
    for (int k = 0; k < 8; ++k) {
        gp[k] = gsrc + (size_t)sub * KT_STRIDE
                     + (size_t)(r0g + k * 16) * 32 + lane * 8;
        lb[k] = sub * HALF_USH + (isB ? 4096 : 0) + k * 512;
    }

    f32x4 acc[4][4];
    #pragma unroll
    for (int a = 0; a < 4; ++a)
        #pragma unroll
        for (int b = 0; b < 4; ++b)
            acc[a][b] = (f32x4){0.f, 0.f, 0.f, 0.f};

    for (int kt = 0; kt < NKT; ++kt) {
        // stage this iteration's 64-wide K-slab (both halves)
        const size_t koff = (size_t)(2 * kt) * KT_STRIDE;
        #pragma unroll
        for (int k = 0; k < 8; ++k)
            async_copy16(gp[k] + koff, &S[lb[k]]);
        __syncthreads();   // drains vmcnt -> buffer ready (m97 pattern)

        #pragma unroll
        for (int h = 0; h < 2; ++h) {
            const unsigned short* base = &S[h * HALF_USH];
            bf16x8 a[4], b[4];
            #pragma unroll
            for (int mt = 0; mt < 4; ++mt) a[mt] = *(const bf16x8*)(base + aoff[mt]);
            #pragma unroll
            for (int nt = 0; nt < 4; ++nt) b[nt] = *(const bf16x8*)(base + boff[nt]);
            __builtin_amdgcn_s_setprio(1);
            #pragma unroll
            for (int mt = 0; mt < 4; ++mt)
                #pragma unroll
                for (int nt = 0; nt < 4; ++nt)
                    acc[mt][nt] = __builtin_amdgcn_mfma_f32_16x16x32_bf16(
                        a[mt], b[nt], acc[mt][nt], 0, 0, 0);
            __builtin_amdgcn_s_setprio(0);
        }
        __syncthreads();   // all waves done reading before next stage overwrites
    }

    // Epilogue: C/D layout col=lane&15, row=quad*4+reg (m89/m91-verified).
    // term = exp(logit_ij - logit_ii) via exp2f; max shifted log2-exp ~99 < 127.
    const float NT_LOG2E = -14.4269504089f;   // -(1/TEMP) * log2(e)
    const float LOG2E    = 1.44269504089f;
    float tsq_l[4];
    #pragma unroll
    for (int nt = 0; nt < 4; ++nt)
        tsq_l[nt] = t_sq[j0 + wn * 64 + nt * 16 + row16];

    #pragma unroll
    for (int mt = 0; mt < 4; ++mt) {
        #pragma unroll
        for (int r = 0; r < 4; ++r) {
            const int i = i0 + wm * 64 + mt * 16 + quad * 4 + r;
            const float psq = p_sq[i];
            const float c0  = -diagl[i] * LOG2E;  // -logit_ii in log2 domain
            float sfin = 0.f;
            #pragma unroll
            for (int nt = 0; nt < 4; ++nt) {
                float c  = acc[mt][nt][r];
                float sq = fmaxf(fmaf(-2.0f, c, psq + tsq_l[nt]), 0.0f);
                float d  = sqrtf(sq);
                float y  = fmaf(d, NT_LOG2E, c0);  // (logit-logit_ii)*log2e
                sfin += exp2f(y);
            }
            #pragma unroll
            for (int m = 1; m < 16; m <<= 1) sfin += __shfl_xor(sfin, m, 64);
            if (row16 == 0) atomicAdd(&rowsum[i], sfin);
        }
    }
}

// K3: final reduction to the 3 output scalars (separate dispatch — fusion
// into the GEMM measured +42 us via the per-block fence/straggler tail, R7).
__global__ void __launch_bounds__(256) finalize_kernel(
    const float* __restrict__ rowsum, const float* __restrict__ magr,
    float* __restrict__ out)
{
    const int tid = threadIdx.x;
    double sc = 0.0, sm = 0.0;
    for (int i = tid; i < B_ROWS; i += 256) {
        sc += log((double)rowsum[i]);   // loss_i = log sum_j exp(logit_ij - logit_ii)
        sm += (double)magr[i];
    }
    #pragma unroll
    for (int m = 1; m < 64; m <<= 1) {
        sc += __shfl_xor(sc, m, 64);
        sm += __shfl_xor(sm, m, 64);
    }
    __shared__ double red[4][2];
    const int wave = tid >> 6, lane = tid & 63;
    if (lane == 0) { red[wave][0] = sc; red[wave][1] = sm; }
    __syncthreads();
    if (tid == 0) {
        sc = red[0][0] + red[1][0] + red[2][0] + red[3][0];
        sm = red[0][1] + red[1][1] + red[2][1] + red[3][1];
        double lc = sc / (double)B_ROWS;
        double lm = sm / (double)B_ROWS;
        out[0] = (float)(0.5 * lc + 0.5 * lm);  // LOSS_SCALE=1, LAMBD=0.5
        out[1] = (float)lc;
        out[2] = (float)lm;
    }
}

extern "C" void kernel_launch(void* const* d_in, const int* in_sizes, int n_in,
                              void* d_out, int out_size, void* d_ws, size_t ws_size,
                              hipStream_t stream) {
    const float* P = (const float*)d_in[0];   // predicted [4096,768] fp32
    const float* T = (const float*)d_in[1];   // target    [4096,768] fp32
    float* out = (float*)d_out;               // 3 fp32 scalars

    // Workspace: Pb at ws+80KB (128-B aligned); nothing before Pb/Tb
    // (R2/R4/R5's 16-B shift lesson).
    char* ws = (char*)d_ws;
    float* rowsum = (float*)ws;               ws += B_ROWS * sizeof(float);
    float* p_sq   = (float*)ws;               ws += B_ROWS * sizeof(float);
    float* t_sq   = (float*)ws;               ws += B_ROWS * sizeof(float);
    float* diagl  = (float*)ws;               ws += B_ROWS * sizeof(float);
    float* magr   = (float*)ws;               ws += B_ROWS * sizeof(float);
    unsigned short* Pb = (unsigned short*)ws; ws += (size_t)B_ROWS * D_DIM * 2;
    unsigned short* Tb = (unsigned short*)ws;

    rowstats_kernel<<<B_ROWS / 4, 256, 0, stream>>>(
        P, T, Pb, Tb, p_sq, t_sq, diagl, magr, rowsum);
    lse_gemm_kernel<<<NBLK, 256, 0, stream>>>(
        Pb, Tb, p_sq, t_sq, diagl, rowsum);
    finalize_kernel<<<1, 256, 0, stream>>>(rowsum, magr, out);
}

// Round 11
// 121.189 us; speedup vs baseline: 1.0887x; 1.0887x over previous
//
#include <hip/hip_runtime.h>
#include <hip/hip_bf16.h>
#include <math.h>

// Problem constants (B=4096 rows, D=768 features)
#define B_ROWS 4096
#define D_DIM  768

// R11 = DIRECT-TO-REGISTER GEMM (no LDS, no barriers in the K-loop).
// Every LDS-staged variant this session pinned at 4-7 TB/s gload_lds
// delivery (R0/R1/R6/R8/R9/R10) regardless of schedule/domains.  This
// kernel reads MFMA fragments straight from the blocked Pb/Tb into VGPRs
// over the plain VMEM->L2 path (measured ceiling 34.5 TB/s, m56), paying
// 2x read duplication (786 MB total) but removing the staging bottleneck
// and every sync point.  Register double-buffered frags, static indexing.
#define BM 128
#define BN 128
#define BK 32
#define NKT (D_DIM / BK)        // 24 K-tiles
#define KT_STRIDE (B_ROWS * 32) // ushorts per BK=32 K-tile block in Pb/Tb
#define NBLK ((B_ROWS / BM) * (B_ROWS / BN))   // 32*32 = 1024 workgroups

typedef __attribute__((ext_vector_type(8))) short bf16x8;  // 8 bf16 = 4 VGPRs (MFMA A/B frag)
typedef __attribute__((ext_vector_type(4))) float f32x4;   // MFMA C/D frag

__device__ __forceinline__ unsigned short f32_to_bf16(float x) {
    // round-to-nearest-even; inputs are finite normals
    unsigned int u = __float_as_uint(x);
    return (unsigned short)((u + 0x7fffu + ((u >> 16) & 1u)) >> 16);
}

// K1: per-row stats + fp32->bf16 conversion into the BLOCKED, PRE-SWIZZLED
// layout Pb[kt32][row][slot] (kt32 = K-tile of 32 elems, 64-B rows, 16-B
// chunk at slot = chunk ^ ((row>>1)&3)).  Unchanged from R8/R9/R10
// (harness-verified).  The slot swizzle is now consumed by the GEMM's
// per-lane load addresses instead of an LDS read.
__global__ void __launch_bounds__(256) rowstats_kernel(
    const float* __restrict__ P, const float* __restrict__ T,
    unsigned short* __restrict__ Pb, unsigned short* __restrict__ Tb,
    float* __restrict__ p_sq, float* __restrict__ t_sq,
    float* __restrict__ diagl, float* __restrict__ magr,
    float* __restrict__ rowsum)
{
    const int wave = threadIdx.x >> 6, lane = threadIdx.x & 63;
    const int i = blockIdx.x * 4 + wave;
    const f32x4* prow = (const f32x4*)(P + (size_t)i * D_DIM);
    const f32x4* trow = (const f32x4*)(T + (size_t)i * D_DIM);
    const int swz = (i >> 1) & 3;

    float psq = 0.f, tsq = 0.f, cr = 0.f, l1 = 0.f, tm = 0.f;
    #pragma unroll
    for (int u = 0; u < 3; ++u) {         // 192 float4 per row / 64 lanes
        const int c4 = u * 64 + lane;
        f32x4 p = prow[c4], t = trow[c4];
        #pragma unroll
        for (int k = 0; k < 4; ++k) {
            psq += p[k] * p[k]; tsq += t[k] * t[k]; cr += p[k] * t[k];
            l1 += fabsf(p[k] - t[k]); tm += fabsf(t[k]);
        }
        // blocked-swizzled destination
        const int kt  = c4 >> 3;                 // 8 float4 = 32 elems per tile
        const int cc  = (c4 >> 1) & 3;           // 16-B chunk within tile row
        const int sub = c4 & 1;                  // 8-B half of the chunk
        const size_t doff = (size_t)kt * KT_STRIDE + (size_t)i * 32
                          + (size_t)(((cc ^ swz) << 3) + (sub << 2));
        *(ushort4*)(Pb + doff) = make_ushort4(f32_to_bf16(p[0]), f32_to_bf16(p[1]),
                                              f32_to_bf16(p[2]), f32_to_bf16(p[3]));
        *(ushort4*)(Tb + doff) = make_ushort4(f32_to_bf16(t[0]), f32_to_bf16(t[1]),
                                              f32_to_bf16(t[2]), f32_to_bf16(t[3]));
    }
    #pragma unroll
    for (int m = 1; m < 64; m <<= 1) {
        psq += __shfl_xor(psq, m, 64);
        tsq += __shfl_xor(tsq, m, 64);
        cr  += __shfl_xor(cr,  m, 64);
        l1  += __shfl_xor(l1,  m, 64);
        tm  += __shfl_xor(tm,  m, 64);
    }
    if (lane == 0) {
        p_sq[i] = psq;
        t_sq[i] = tsq;
        float sq = fmaxf(psq + tsq - 2.0f * cr, 0.0f);
        diagl[i] = -sqrtf(sq) * 10.0f;    // logit_ii = -dist/0.1 (the LSE shift)
        magr[i]  = l1 / tm;
        rowsum[i] = 0.0f;
    }
}

// K2: bf16-MFMA cross GEMM + LSE epilogue, direct-to-register.
// 128x128 tile, 4 waves (2x2), per-wave output 64x64 (acc[4][4]).
//
// Fragment load (per wave, per K-tile): 4 A-frags + 4 B-frags, each one
// global_load_dwordx4: lane (row16,quad) reads 16 B at
//   base + (rowbase+row16)*64B + (quad ^ ((row16>>1)&3))*16B
// == 1 KB fully contiguous in the blocked layout (64-B rows, slots
// pre-swizzled by rowstats; the XOR here undoes it -> correct chunk).
// MFMA A/B layout: lane (row16,quad) holds k = quad*8..quad*8+7 of row
// row16 -- exactly the 16 B loaded (same mapping verified all session via
// the LDS path; only the transport changed).
//
// K-loop: register double-buffer (two named frag sets, 2x unrolled loop --
// static indexing per rule #20), loads of tile t+1 issued before MFMA of
// tile t; compiler inserts the vmcnt waits.  NO barriers, NO LDS.
__global__ void __launch_bounds__(256, 3) lse_gemm_kernel(
    const unsigned short* __restrict__ Pb, const unsigned short* __restrict__ Tb,
    const float* __restrict__ p_sq, const float* __restrict__ t_sq,
    const float* __restrict__ diagl, float* __restrict__ rowsum)
{
    const int tid  = threadIdx.x;
    const int lane = tid & 63, wave = tid >> 6;

    // XCD-aware swizzle (bijective over 1024 blocks): tile grid 32x32;
    // XCD x gets a 16(ti) x 8(tj) chunk -> A 3 MB + B 1.5 MB panel in L2.
    const int flat = blockIdx.x;
    const int xcd  = flat & 7;
    const int s    = flat >> 3;                      // 0..127: slot within XCD
    const int ti   = ((xcd & 1) << 4) + (s & 15);    // 0..31
    const int tj   = ((xcd >> 1) << 3) + (s >> 4);   // 0..31
    const int i0   = ti * BM, j0 = tj * BN;

    // compute mapping: 2x2 wave grid, per-wave output 64(M) x 64(N)
    const int wm = wave >> 1, wn = wave & 1;
    const int row16 = lane & 15, quad = lane >> 4;
    const int slot  = quad ^ ((row16 >> 1) & 3);     // chunk-XOR de-swizzle

    // per-lane frag pointers (ushort units), advanced by KT_STRIDE per tile
    const unsigned short* ap[4];
    const unsigned short* bp[4];
    #pragma unroll
    for (int mt = 0; mt < 4; ++mt)
        ap[mt] = Pb + (size_t)(i0 + wm * 64 + mt * 16 + row16) * 32 + slot * 8;
    #pragma unroll
    for (int nt = 0; nt < 4; ++nt)
        bp[nt] = Tb + (size_t)(j0 + wn * 64 + nt * 16 + row16) * 32 + slot * 8;

    f32x4 acc[4][4];
    #pragma unroll
    for (int a = 0; a < 4; ++a)
        #pragma unroll
        for (int b = 0; b < 4; ++b)
            acc[a][b] = (f32x4){0.f, 0.f, 0.f, 0.f};

    // two named register frag sets (static indexing; no runtime-indexed arrays)
    bf16x8 a0[4], b0[4], a1[4], b1[4];

    #pragma unroll
    for (int f = 0; f < 4; ++f) {
        a0[f] = *(const bf16x8*)(ap[f]);
        b0[f] = *(const bf16x8*)(bp[f]);
    }

    // 24 tiles, unrolled x2: even tiles in set0, odd in set1.
    #pragma unroll
    for (int t = 0; t < NKT; t += 2) {
        // issue loads for tile t+1 (set1) before computing tile t (set0)
        {
            const size_t o1 = (size_t)(t + 1) * KT_STRIDE;
            #pragma unroll
            for (int f = 0; f < 4; ++f) {
                a1[f] = *(const bf16x8*)(ap[f] + o1);
                b1[f] = *(const bf16x8*)(bp[f] + o1);
            }
        }
        __builtin_amdgcn_s_setprio(1);
        #pragma unroll
        for (int mt = 0; mt < 4; ++mt)
            #pragma unroll
            for (int nt = 0; nt < 4; ++nt)
                acc[mt][nt] = __builtin_amdgcn_mfma_f32_16x16x32_bf16(
                    a0[mt], b0[nt], acc[mt][nt], 0, 0, 0);
        __builtin_amdgcn_s_setprio(0);

        // issue loads for tile t+2 (set0) before computing tile t+1 (set1)
        if (t + 2 < NKT) {
            const size_t o2 = (size_t)(t + 2) * KT_STRIDE;
            #pragma unroll
            for (int f = 0; f < 4; ++f) {
                a0[f] = *(const bf16x8*)(ap[f] + o2);
                b0[f] = *(const bf16x8*)(bp[f] + o2);
            }
        }
        __builtin_amdgcn_s_setprio(1);
        #pragma unroll
        for (int mt = 0; mt < 4; ++mt)
            #pragma unroll
            for (int nt = 0; nt < 4; ++nt)
                acc[mt][nt] = __builtin_amdgcn_mfma_f32_16x16x32_bf16(
                    a1[mt], b1[nt], acc[mt][nt], 0, 0, 0);
        __builtin_amdgcn_s_setprio(0);
    }

    // Epilogue: C/D layout col=lane&15, row=quad*4+reg (m89/m91-verified).
    // term = exp(logit_ij - logit_ii) via exp2f; max shifted log2-exp ~99 < 127.
    const float NT_LOG2E = -14.4269504089f;   // -(1/TEMP) * log2(e)
    const float LOG2E    = 1.44269504089f;
    float tsq_l[4];
    #pragma unroll
    for (int nt = 0; nt < 4; ++nt)
        tsq_l[nt] = t_sq[j0 + wn * 64 + nt * 16 + row16];

    #pragma unroll
    for (int mt = 0; mt < 4; ++mt) {
        #pragma unroll
        for (int r = 0; r < 4; ++r) {
            const int i = i0 + wm * 64 + mt * 16 + quad * 4 + r;
            const float psq = p_sq[i];
            const float c0  = -diagl[i] * LOG2E;  // -logit_ii in log2 domain
            float sfin = 0.f;
            #pragma unroll
            for (int nt = 0; nt < 4; ++nt) {
                float c  = acc[mt][nt][r];
                float sq = fmaxf(fmaf(-2.0f, c, psq + tsq_l[nt]), 0.0f);
                float d  = sqrtf(sq);
                float y  = fmaf(d, NT_LOG2E, c0);  // (logit-logit_ii)*log2e
                sfin += exp2f(y);
            }
            #pragma unroll
            for (int m = 1; m < 16; m <<= 1) sfin += __shfl_xor(sfin, m, 64);
            if (row16 == 0) atomicAdd(&rowsum[i], sfin);
        }
    }
}

// K3: final reduction to the 3 output scalars (separate dispatch — fusion
// into the GEMM measured +42 us via the per-block fence/straggler tail, R7).
__global__ void __launch_bounds__(256) finalize_kernel(
    const float* __restrict__ rowsum, const float* __restrict__ magr,
    float* __restrict__ out)
{
    const int tid = threadIdx.x;
    double sc = 0.0, sm = 0.0;
    for (int i = tid; i < B_ROWS; i += 256) {
        sc += log((double)rowsum[i]);   // loss_i = log sum_j exp(logit_ij - logit_ii)
        sm += (double)magr[i];
    }
    #pragma unroll
    for (int m = 1; m < 64; m <<= 1) {
        sc += __shfl_xor(sc, m, 64);
        sm += __shfl_xor(sm, m, 64);
    }
    __shared__ double red[4][2];
    const int wave = tid >> 6, lane = tid & 63;
    if (lane == 0) { red[wave][0] = sc; red[wave][1] = sm; }
    __syncthreads();
    if (tid == 0) {
        sc = red[0][0] + red[1][0] + red[2][0] + red[3][0];
        sm = red[0][1] + red[1][1] + red[2][1] + red[3][1];
        double lc = sc / (double)B_ROWS;
        double lm = sm / (double)B_ROWS;
        out[0] = (float)(0.5 * lc + 0.5 * lm);  // LOSS_SCALE=1, LAMBD=0.5
        out[1] = (float)lc;
        out[2] = (float)lm;
    }
}

extern "C" void kernel_launch(void* const* d_in, const int* in_sizes, int n_in,
                              void* d_out, int out_size, void* d_ws, size_t ws_size,
                              hipStream_t stream) {
    const float* P = (const float*)d_in[0];   // predicted [4096,768] fp32
    const float* T = (const float*)d_in[1];   // target    [4096,768] fp32
    float* out = (float*)d_out;               // 3 fp32 scalars

    // Workspace: Pb at ws+80KB (128-B aligned); nothing before Pb/Tb
    // (R2/R4/R5's 16-B shift lesson).
    char* ws = (char*)d_ws;
    float* rowsum = (float*)ws;               ws += B_ROWS * sizeof(float);
    float* p_sq   = (float*)ws;               ws += B_ROWS * sizeof(float);
    float* t_sq   = (float*)ws;               ws += B_ROWS * sizeof(float);
    float* diagl  = (float*)ws;               ws += B_ROWS * sizeof(float);
    float* magr   = (float*)ws;               ws += B_ROWS * sizeof(float);
    unsigned short* Pb = (unsigned short*)ws; ws += (size_t)B_ROWS * D_DIM * 2;
    unsigned short* Tb = (unsigned short*)ws;

    rowstats_kernel<<<B_ROWS / 4, 256, 0, stream>>>(
        P, T, Pb, Tb, p_sq, t_sq, diagl, magr, rowsum);
    lse_gemm_kernel<<<NBLK, 256, 0, stream>>>(
        Pb, Tb, p_sq, t_sq, diagl, rowsum);
    finalize_kernel<<<1, 256, 0, stream>>>(rowsum, magr, out);
}